// Round 5
// baseline (1042.461 us; speedup 1.0000x reference)
//
#include <hip/hip_runtime.h>
#include <math.h>

#define NB 16
#define NCH 16
#define NL 13
#define NN 1024
#define NT 12
#define NLAY 8
#define MROWS 208          // NCH*NL valid rows
#define MPAD 256           // padded plane rows

typedef _Float16 f16;
typedef __attribute__((ext_vector_type(8))) _Float16 f16x8;
typedef __attribute__((ext_vector_type(16))) float f32x16;

// ---------------- workspace layout (float offsets) ----------------
#define OFF_TAB   0
#define OFF_ADP   1024
#define OFF_M     (OFF_ADP  + (size_t)NB*1024)
#define OFF_SRC   (OFF_M    + (size_t)NB*1024)
#define OFF_TEMP  (OFF_SRC  + (size_t)NB*NN*32)
#define OFF_AH    (OFF_TEMP + (size_t)NB*NN*32)                 // A f16 [b][1024][1024]
#define OFF_XH    (OFF_AH   + (size_t)NB*NN*NN/2)               // xs hi f16 [b][256][1024]
#define OFF_XL    (OFF_XH   + (size_t)NB*MPAD*NN/2)
#define OFF_H1H   (OFF_XL   + (size_t)NB*MPAD*NN/2)
#define OFF_H1L   (OFF_H1H  + (size_t)NB*MPAD*NN/2)
#define OFF_H2    (OFF_H1L  + (size_t)NB*MPAD*NN/2)             // out1 partials for end stage
#define OFF_X     (OFF_H2   + (size_t)NB*MPAD*NN)               // x f32 [b][208][1024]
#define OFF_SKIP  (OFF_X    + (size_t)NB*MROWS*NN)              // skip f32 [b][832][1024]
#define WS_FLOATS (OFF_SKIP + (size_t)NB*832*NN)

__device__ __forceinline__ void gload16(const void* g, void* l) {
    __builtin_amdgcn_global_load_lds(
        (const __attribute__((address_space(1))) unsigned int*)g,
        (__attribute__((address_space(3))) unsigned int*)l,
        16, 0, 0);
}

__device__ __forceinline__ float fast_tanh(float x) {
    float e = __expf(2.0f * x);
    return 1.0f - 2.0f / (e + 1.0f);
}

// ---------------- tables: bn scale + x_a affine recurrence ----------------
__global__ void k_tables(const float* __restrict__ bn_g,
                         const float* __restrict__ bna_g, const float* __restrict__ bna_b,
                         const float* __restrict__ sa_w, const float* __restrict__ sa_b,
                         float* __restrict__ tab) {
    int c = threadIdx.x;
    if (c >= 16) return;
    float inv = 1.0f / sqrtf(1.0f + 1e-5f);
    float A = sa_w[c], Bc = sa_b[c];
    for (int i = 0; i < NLAY; i++) {
        tab[i*16 + c]       = bn_g[i*16 + c] * inv;
        tab[128 + i*16 + c] = A;
        tab[256 + i*16 + c] = Bc;
        float ga = bna_g[i*16 + c] * inv;
        A  = 2.0f * ga * A;
        Bc = 2.0f * ga * Bc + bna_b[i*16 + c];
    }
}

// ---------------- start conv + fc layer 0 ----------------
__global__ __launch_bounds__(256) void k_startfc(const float* __restrict__ inp,
                        const float* __restrict__ sw, const float* __restrict__ sb,
                        const float* __restrict__ fc1, const float* __restrict__ fc2,
                        const float* __restrict__ skw, const float* __restrict__ skb,
                        float* __restrict__ x, f16* __restrict__ xh, f16* __restrict__ xl,
                        float* __restrict__ skip) {
    __shared__ float W1[256], W2[256], W3[128], B3[8], SW[16], SB[16];
    int t = threadIdx.x;
    if (t < 256) { W1[t] = fc1[t]; W2[t] = fc2[t]; }
    if (t < 128) W3[t] = skw[t];             // layer 0
    if (t < 8)   B3[t] = skb[t];
    if (t < 16)  { SW[t] = sw[t]; SB[t] = sb[t]; }
    __syncthreads();
    int idx = blockIdx.x*256 + t;            // over (b,l,n)
    int n = idx & 1023;
    int q = idx >> 10;
    int l = q % 13, b = q / 13;
    float u = (l == 0) ? 0.f : inp[((size_t)(b*2 + 0)*NN + n)*NT + (l - 1)];
    float v[16], t1[16], v2[16];
    #pragma unroll
    for (int c = 0; c < 16; c++) {
        v[c] = SW[c]*u + SB[c];
        x[((size_t)b*MROWS + c*13 + l)*NN + n] = v[c];
    }
    #pragma unroll
    for (int c = 0; c < 16; c++) {
        float s = 0.f;
        #pragma unroll
        for (int j = 0; j < 16; j++) s += W1[c*16 + j] * v[j];
        t1[c] = fmaxf(s, 0.f);
    }
    #pragma unroll
    for (int c = 0; c < 16; c++) {
        float s = 0.f;
        #pragma unroll
        for (int j = 0; j < 16; j++) s += W2[c*16 + j] * t1[j];
        float z = 2.f*s + v[c];
        v2[c] = 1.f / (1.f + __expf(-z));
        size_t o = ((size_t)b*MPAD + c*13 + l)*NN + n;
        f16 hi = (f16)v2[c];
        xh[o] = hi;
        xl[o] = (f16)(v2[c] - (float)hi);
    }
    #pragma unroll
    for (int sc = 0; sc < 8; sc++) {
        float s = B3[sc];
        #pragma unroll
        for (int c = 0; c < 16; c++) s += W3[sc*16 + c] * v2[c];
        skip[((size_t)b*832 + 7*104 + sc*13 + l)*NN + n] = s;
    }
}

// ---------------- adp / M (one block per batch, tiny) ----------------
__global__ __launch_bounds__(256) void k_adp(const float* __restrict__ p1, const int* __restrict__ ind,
                      const float* __restrict__ pk, const float* __restrict__ p3,
                      float* __restrict__ adpg, float* __restrict__ Mg) {
    __shared__ float te[32];
    __shared__ float adp[32][32];
    __shared__ float p3s[32][32];
    int b = blockIdx.x, t = threadIdx.x;
    if (t < 32) te[t] = p1[(size_t)ind[b]*32 + t];
    for (int i = t; i < 1024; i += 256) p3s[i >> 5][i & 31] = p3[i];
    __syncthreads();
    for (int i = t; i < 1024; i += 256) {
        float s = 0.f;
        for (int q = 0; q < 32; q++) s += te[q] * pk[q*1024 + i];
        adp[i >> 5][i & 31] = s;
        adpg[(size_t)b*1024 + i] = s;
    }
    __syncthreads();
    for (int i = t; i < 1024; i += 256) {
        int j = i >> 5, c = i & 31;
        float s = 0.f;
        for (int k = 0; k < 32; k++) s += adp[j][k] * p3s[c][k];
        Mg[(size_t)b*1024 + i] = s;
    }
}

// ---------------- src/temp: 8 blocks per batch ----------------
__global__ __launch_bounds__(256) void k_st(const float* __restrict__ p2, const float* __restrict__ adpg,
                     const float* __restrict__ Mg,
                     float* __restrict__ src, float* __restrict__ temp) {
    __shared__ float adpS[32][32], MS[32][32], p2S[128][32];
    int b = blockIdx.y, n0 = blockIdx.x * 128, t = threadIdx.x;
    for (int i = t; i < 1024; i += 256) {
        adpS[i >> 5][i & 31] = adpg[(size_t)b*1024 + i];
        MS[i >> 5][i & 31]   = Mg[(size_t)b*1024 + i];
    }
    for (int i = t; i < 128*32; i += 256) p2S[i >> 5][i & 31] = p2[(size_t)(n0 + (i >> 5))*32 + (i & 31)];
    __syncthreads();
    int k = t & 31, g = t >> 5;
    for (int nn = g; nn < 128; nn += 8) {
        float rs = 0.f, rt = 0.f;
        #pragma unroll 8
        for (int j = 0; j < 32; j++) {
            float pv = p2S[nn][j];
            rs += pv * adpS[j][k];
            rt += pv * MS[j][k];
        }
        src [((size_t)b*NN + n0 + nn)*32 + k] = rs;
        temp[((size_t)b*NN + n0 + nn)*32 + k] = rt;
    }
}

// ---------------- A tiles: triangular grid, transposed-LDS float4 dots ----------------
__global__ __launch_bounds__(256) void k_A(const float* __restrict__ src, const float* __restrict__ temp,
                    f16* __restrict__ Amat) {
    int b = blockIdx.z;
    int r = blockIdx.x, ti = 0;
    while (r >= 16 - ti) { r -= 16 - ti; ti++; }
    int tj = ti + r;
    int n0 = ti*64, m0 = tj*64;
    __shared__ float snT[32][68], tmT[32][68], smT[32][68], tnT[32][68];
    __shared__ f16 At[64][72];
    int t = threadIdx.x;
    const float* sb_ = src  + (size_t)b*NN*32;
    const float* tb_ = temp + (size_t)b*NN*32;
    for (int i = t; i < 64*32; i += 256) {
        int rr = i >> 5, k = i & 31;
        snT[k][rr] = sb_[(n0 + rr)*32 + k];
        tmT[k][rr] = tb_[(m0 + rr)*32 + k];
        smT[k][rr] = sb_[(m0 + rr)*32 + k];
        tnT[k][rr] = tb_[(n0 + rr)*32 + k];
    }
    __syncthreads();
    int tr = (t >> 4) * 4, tc = (t & 15) * 4;
    float acc1[4][4] = {}, acc2[4][4] = {};
    #pragma unroll 4
    for (int k = 0; k < 32; k++) {
        float4 a  = *(const float4*)&snT[k][tr];
        float4 bb = *(const float4*)&tmT[k][tc];
        float4 c2 = *(const float4*)&smT[k][tc];
        float4 d2 = *(const float4*)&tnT[k][tr];
        float av[4] = {a.x, a.y, a.z, a.w};
        float bv[4] = {bb.x, bb.y, bb.z, bb.w};
        float cv[4] = {c2.x, c2.y, c2.z, c2.w};
        float dv[4] = {d2.x, d2.y, d2.z, d2.w};
        #pragma unroll
        for (int i = 0; i < 4; i++)
            #pragma unroll
            for (int jj = 0; jj < 4; jj++) { acc1[i][jj] += av[i]*bv[jj]; acc2[i][jj] += cv[jj]*dv[i]; }
    }
    #pragma unroll
    for (int i = 0; i < 4; i++)
        #pragma unroll
        for (int jj = 0; jj < 4; jj++) {
            float v = fast_tanh(acc1[i][jj] - acc2[i][jj]);
            Amat[((size_t)b*NN + n0 + tr + i)*NN + m0 + tc + jj] = (f16)(v > 0.f ? v : 0.f);
            At[tc + jj][tr + i] = (f16)(-v > 0.f ? -v : 0.f);
        }
    __syncthreads();
    for (int i = t; i < 512; i += 256) {
        int rr = i >> 3, c8 = (i & 7) * 8;
        f16* dst = &Amat[((size_t)b*NN + m0 + rr)*NN + n0 + c8];
        #pragma unroll
        for (int k = 0; k < 8; k++) dst[k] = At[rr][c8 + k];
    }
}

// ---------------- hop1 MFMA GEMM (unchanged structure): h1 = (Xh+Xl)·A^T ----------------
__global__ __launch_bounds__(256) void k_gmm(const f16* __restrict__ Xh, const f16* __restrict__ Xl,
                     const f16* __restrict__ Ag, f16* __restrict__ Ch, f16* __restrict__ Cl) {
    __shared__ alignas(16) f16 As[2][128*64];
    __shared__ alignas(16) f16 Xs[2][2*64*64];
    const int bid = blockIdx.x;                // 0..511
    const int xcd = bid & 7;
    const int j   = bid >> 3;
    const int b   = xcd + ((j >> 5) << 3);
    const int tile = j & 31;
    const int my  = tile >> 3;
    const int n0  = (tile & 7) * 128;
    const int t = threadIdx.x;
    const int w = t >> 6, lane = t & 63;
    const char* Ab  = (const char*)(Ag + (size_t)b*NN*NN);
    const char* Xhb = (const char*)(Xh + (size_t)b*MPAD*NN);
    const char* Xlb = (const char*)(Xl + (size_t)b*MPAD*NN);

    const char* asrc[4];
    int adst[4];
    const char* xsrc[4];
    int xdst[4];
    {
        const char* Abase = Ab + (size_t)n0*2048;
        const char* Xb0 = Xhb + (size_t)(my*64)*2048;
        const char* Xb1 = Xlb + (size_t)(my*64)*2048;
        #pragma unroll
        for (int rr = 0; rr < 4; ++rr) {
            int q = rr*4 + w;
            int slot = q*64 + lane;
            int row = slot >> 3, ch = slot & 7;
            asrc[rr] = Abase + (size_t)row*2048 + ((ch ^ (row & 7)) << 4);
            adst[rr] = q*1024;
            int xrow = row & 63;
            xsrc[rr] = ((q >> 3) ? Xb1 : Xb0) + (size_t)xrow*2048 + ((ch ^ (xrow & 7)) << 4);
            xdst[rr] = q*1024;
        }
    }

    const int wm = (w >> 1) * 32, wn = (w & 1) * 64;
    const int kh = lane >> 5;
    const int arow = wm + (lane & 31);
    const int brow0 = wn + (lane & 31);
    const int brow1 = brow0 + 32;
    const int swa = arow & 7, swb0 = brow0 & 7, swb1 = brow1 & 7;

    f32x16 acc0 = {}, acc1 = {};

    auto stage = [&](int buf, int it) {
        size_t koff = (size_t)it * 128;
        #pragma unroll
        for (int rr = 0; rr < 4; ++rr)
            gload16(asrc[rr] + koff, (char*)As[buf] + adst[rr]);
        #pragma unroll
        for (int rr = 0; rr < 4; ++rr)
            gload16(xsrc[rr] + koff, (char*)Xs[buf] + xdst[rr]);
    };
    auto compute = [&](int buf) {
        const char* aP0 = (const char*)Xs[buf] + (size_t)arow*128;
        const char* aP1 = aP0 + 8192;
        const char* bP0 = (const char*)As[buf] + (size_t)brow0*128;
        const char* bP1 = (const char*)As[buf] + (size_t)brow1*128;
        #pragma unroll
        for (int s = 0; s < 4; ++s) {
            int cn = s*2 + kh;
            f16x8 ah = *(const f16x8*)(aP0 + ((cn ^ swa) << 4));
            f16x8 al = *(const f16x8*)(aP1 + ((cn ^ swa) << 4));
            f16x8 b0 = *(const f16x8*)(bP0 + ((cn ^ swb0) << 4));
            f16x8 b1 = *(const f16x8*)(bP1 + ((cn ^ swb1) << 4));
            acc0 = __builtin_amdgcn_mfma_f32_32x32x16_f16(ah, b0, acc0, 0, 0, 0);
            acc1 = __builtin_amdgcn_mfma_f32_32x32x16_f16(ah, b1, acc1, 0, 0, 0);
            acc0 = __builtin_amdgcn_mfma_f32_32x32x16_f16(al, b0, acc0, 0, 0, 0);
            acc1 = __builtin_amdgcn_mfma_f32_32x32x16_f16(al, b1, acc1, 0, 0, 0);
        }
    };

    stage(0, 0);
    int cur = 0;
    for (int it = 0; it < 15; ++it) {
        stage(cur ^ 1, it + 1);
        asm volatile("s_waitcnt vmcnt(8)" ::: "memory");
        __builtin_amdgcn_s_barrier();
        compute(cur);
        __builtin_amdgcn_s_barrier();
        cur ^= 1;
    }
    asm volatile("s_waitcnt vmcnt(0)" ::: "memory");
    __builtin_amdgcn_s_barrier();
    compute(cur);

    const int coll = lane & 31;
    #pragma unroll
    for (int reg = 0; reg < 16; ++reg) {
        int m = my*64 + wm + (reg & 3) + 8*(reg >> 2) + 4*kh;
        if (m < MROWS) {
            size_t o0 = ((size_t)b*MPAD + m)*NN + n0 + wn + coll;
            float v0 = acc0[reg], v1 = acc1[reg];
            f16 h0 = (f16)v0; Ch[o0]      = h0; Cl[o0]      = (f16)(v0 - (float)h0);
            f16 h1 = (f16)v1; Ch[o0 + 32] = h1; Cl[o0 + 32] = (f16)(v1 - (float)h1);
        }
    }
}

// ---------------- fused hop2 GEMM + epilogue + fc(next): k_g2e ----------------
// BM=256 (all rows) x BN=64, BK=32 double-buffered. h2 stays in regs/LDS.
__global__ __launch_bounds__(256) void k_g2e(
        const f16* __restrict__ h1h, const f16* __restrict__ h1l,
        const f16* __restrict__ Ag,
        f16* __restrict__ xh, f16* __restrict__ xl,
        float* __restrict__ x, const float* __restrict__ inp,
        const float* __restrict__ gw, const float* __restrict__ gb,
        const float* __restrict__ bnb, const float* __restrict__ tab,
        const float* __restrict__ fc1, const float* __restrict__ fc2,
        const float* __restrict__ skw, const float* __restrict__ skb,
        float* __restrict__ skip, int layer) {
    __shared__ alignas(16) char lds[2*36864];       // stage buffers; reused as H2 f32[256][64]
    __shared__ float Wg[768], W1s[256], W2s[256], W3s[128], B3s[8];
    __shared__ float GBs[16], BNBs[16], BNSs[16], ACs[16], BCs[16];
    const int bid = blockIdx.x;                     // 0..255
    const int xcd = bid & 7, g = bid >> 3;
    const int b   = xcd + ((g & 1) << 3);
    const int n0  = (g >> 1) * 64;
    const int t = threadIdx.x, w = t >> 6, lane = t & 63;
    const int nl = layer + 1;

    // staging source pointers (k0 = 0); advance 64 B per K-step
    const char* sp[9];
    {
        const char* H0 = (const char*)(h1h + (size_t)b*MPAD*NN);
        const char* H1 = (const char*)(h1l + (size_t)b*MPAD*NN);
        const char* Ab = (const char*)(Ag  + (size_t)b*NN*NN);
        #pragma unroll
        for (int i = 0; i < 8; ++i) {
            int s16 = (i & 3)*256 + t;
            int row = s16 >> 2, ch = s16 & 3;
            sp[i] = ((i < 4) ? H0 : H1) + (size_t)row*2048 + ((ch ^ (row & 3)) << 4);
        }
        int row = t >> 2, ch = t & 3;
        sp[8] = Ab + (size_t)(n0 + row)*2048 + ((ch ^ (row & 3)) << 4);
    }

    f32x16 acc00 = {}, acc01 = {}, acc10 = {}, acc11 = {};
    const int r0 = w*64 + (lane & 31);
    const int kh = lane >> 5;
    const int c0 = lane & 31;
    const int swA = r0 & 3, swB0 = c0 & 3;          // (r0+32)&3 == r0&3, (c0+32)&3 == c0&3

    auto stage = [&](int buf, int it) {
        size_t koff = (size_t)it * 64;
        char* dbase = lds + buf*36864 + w*1024;
        #pragma unroll
        for (int i = 0; i < 9; ++i)
            gload16(sp[i] + koff, dbase + i*4096);
    };
    auto compute = [&](int buf) {
        const char* H = lds + buf*36864;
        const char* Areg = H + 32768;
        #pragma unroll
        for (int s = 0; s < 2; ++s) {
            int cn = s*2 + kh;
            const char* a0p = H + r0*64 + ((cn ^ swA) << 4);
            const char* a1p = a0p + 32*64;
            f16x8 a0h = *(const f16x8*)(a0p);
            f16x8 a0l = *(const f16x8*)(a0p + 16384);
            f16x8 a1h = *(const f16x8*)(a1p);
            f16x8 a1l = *(const f16x8*)(a1p + 16384);
            const char* b0p = Areg + c0*64 + ((cn ^ swB0) << 4);
            const char* b1p = b0p + 32*64;
            f16x8 bb0 = *(const f16x8*)b0p;
            f16x8 bb1 = *(const f16x8*)b1p;
            acc00 = __builtin_amdgcn_mfma_f32_32x32x16_f16(a0h, bb0, acc00, 0, 0, 0);
            acc01 = __builtin_amdgcn_mfma_f32_32x32x16_f16(a0h, bb1, acc01, 0, 0, 0);
            acc10 = __builtin_amdgcn_mfma_f32_32x32x16_f16(a1h, bb0, acc10, 0, 0, 0);
            acc11 = __builtin_amdgcn_mfma_f32_32x32x16_f16(a1h, bb1, acc11, 0, 0, 0);
            acc00 = __builtin_amdgcn_mfma_f32_32x32x16_f16(a0l, bb0, acc00, 0, 0, 0);
            acc01 = __builtin_amdgcn_mfma_f32_32x32x16_f16(a0l, bb1, acc01, 0, 0, 0);
            acc10 = __builtin_amdgcn_mfma_f32_32x32x16_f16(a1l, bb0, acc10, 0, 0, 0);
            acc11 = __builtin_amdgcn_mfma_f32_32x32x16_f16(a1l, bb1, acc11, 0, 0, 0);
        }
    };

    stage(0, 0);
    // weights -> LDS (issued after first stage; compiler drains their loads on ds_write)
    for (int i = t; i < 768; i += 256) Wg[i] = gw[layer*768 + i];
    if (t < 256) { W1s[t] = fc1[t]; W2s[t] = fc2[t]; }
    if (t < 128) W3s[t] = skw[nl*128 + t];
    if (t < 8)   B3s[t] = skb[nl*8 + t];
    if (t < 16) {
        GBs[t]  = gb[layer*16 + t];
        BNBs[t] = bnb[layer*16 + t];
        BNSs[t] = tab[layer*16 + t];
        ACs[t]  = tab[128 + layer*16 + t];
        BCs[t]  = tab[256 + layer*16 + t];
    }

    int cur = 0;
    for (int it = 0; it < 31; ++it) {
        stage(cur ^ 1, it + 1);
        asm volatile("s_waitcnt vmcnt(9)" ::: "memory");
        __builtin_amdgcn_s_barrier();
        compute(cur);
        __builtin_amdgcn_s_barrier();
        cur ^= 1;
    }
    asm volatile("s_waitcnt vmcnt(0)" ::: "memory");
    __builtin_amdgcn_s_barrier();
    compute(cur);
    __builtin_amdgcn_s_barrier();                   // everyone done reading stage LDS

    // acc -> LDS H2 f32 [256][64] (overlaps stage buffers)
    float* H2 = (float*)lds;
    #pragma unroll
    for (int reg = 0; reg < 16; ++reg) {
        int mrow = (reg & 3) + 8*(reg >> 2) + 4*kh;
        H2[(w*64 + mrow)*64      + c0     ] = acc00[reg];
        H2[(w*64 + mrow)*64      + c0 + 32] = acc01[reg];
        H2[(w*64 + 32 + mrow)*64 + c0     ] = acc10[reg];
        H2[(w*64 + 32 + mrow)*64 + c0 + 32] = acc11[reg];
    }
    __syncthreads();

    // epilogue: per (l, n) position do gconv + bn + fc(next) + skip
    for (int pos = t; pos < 13*64; pos += 256) {
        int l = pos >> 6, n = pos & 63;
        int gn = n0 + n;
        float u1 = (l == 0) ? 0.f : inp[((size_t)(b*2 + 1)*NN + gn)*NT + (l - 1)];
        float vx[16], v1[16], v2[16], xnew[16];
        #pragma unroll
        for (int c = 0; c < 16; c++) {
            int m = c*13 + l;
            size_t op = ((size_t)b*MPAD + m)*NN + gn;
            vx[c] = (float)xh[op] + (float)xl[op];
            v1[c] = (float)h1h[op] + (float)h1l[op];
            v2[c] = H2[m*64 + n];
        }
        #pragma unroll
        for (int o = 0; o < 16; o++) {
            float s = GBs[o];
            #pragma unroll
            for (int c = 0; c < 16; c++) s += Wg[o*48 + c]      * vx[c];
            #pragma unroll
            for (int c = 0; c < 16; c++) s += Wg[o*48 + 16 + c] * v1[c];
            #pragma unroll
            for (int c = 0; c < 16; c++) s += Wg[o*48 + 32 + c] * v2[c];
            float xa = ACs[o]*u1 + BCs[o];
            float vo = x[((size_t)b*MROWS + o*13 + l)*NN + gn];
            xnew[o] = BNSs[o]*(s + xa + vo) + BNBs[o];
        }
        if (layer < 6) {
            #pragma unroll
            for (int o = 0; o < 16; o++)
                x[((size_t)b*MROWS + o*13 + l)*NN + gn] = xnew[o];
        }
        float t1[16], vs[16];
        #pragma unroll
        for (int c = 0; c < 16; c++) {
            float s = 0.f;
            #pragma unroll
            for (int j = 0; j < 16; j++) s += W1s[c*16 + j] * xnew[j];
            t1[c] = fmaxf(s, 0.f);
        }
        #pragma unroll
        for (int c = 0; c < 16; c++) {
            float s = 0.f;
            #pragma unroll
            for (int j = 0; j < 16; j++) s += W2s[c*16 + j] * t1[j];
            float z = 2.f*s + xnew[c];
            vs[c] = 1.f / (1.f + __expf(-z));
            if (layer < 6) {
                size_t o = ((size_t)b*MPAD + c*13 + l)*NN + gn;
                f16 hi = (f16)vs[c];
                xh[o] = hi;
                xl[o] = (f16)(vs[c] - (float)hi);
            }
        }
        #pragma unroll
        for (int sc = 0; sc < 8; sc++) {
            float s = B3s[sc];
            #pragma unroll
            for (int c = 0; c < 16; c++) s += W3s[sc*16 + c] * vs[c];
            skip[((size_t)b*832 + (7 - nl)*104 + sc*13 + l)*NN + gn] = s;
        }
    }
}

// ---------------- end stage 1: split-K partial GEMM ----------------
__global__ __launch_bounds__(256) void k_end1(const float* __restrict__ skip, const float* __restrict__ w1,
                       float* __restrict__ out1) {
    __shared__ alignas(16) float Ws[52][68];
    __shared__ alignas(16) float Ss[52][68];
    int n0 = blockIdx.x * 64, ks = blockIdx.y, b = blockIdx.z;
    int t = threadIdx.x, ty = t >> 4, tx = t & 15;
    float acc[4][4] = {};
    int kbase = ks * 208;
    for (int kk = 0; kk < 4; kk++) {
        int k0 = kbase + kk*52;
        for (int i = t; i < 52*64; i += 256) {
            int r = i >> 6, c = i & 63;
            float sv = skip[((size_t)b*832 + k0 + r)*NN + n0 + c];
            Ss[r][c] = sv > 0.f ? sv : 0.f;
            Ws[r][c] = w1[(size_t)c*832 + k0 + r];
        }
        __syncthreads();
        #pragma unroll 4
        for (int k = 0; k < 52; k++) {
            float4 av = *(const float4*)&Ws[k][ty*4];
            float4 bv = *(const float4*)&Ss[k][tx*4];
            float a[4] = {av.x, av.y, av.z, av.w};
            float bb[4] = {bv.x, bv.y, bv.z, bv.w};
            #pragma unroll
            for (int i = 0; i < 4; i++)
                #pragma unroll
                for (int jj = 0; jj < 4; jj++) acc[i][jj] += a[i]*bb[jj];
        }
        __syncthreads();
    }
    #pragma unroll
    for (int i = 0; i < 4; i++)
        #pragma unroll
        for (int jj = 0; jj < 4; jj++)
            out1[(((size_t)ks*NB + b)*64 + ty*4 + i)*NN + n0 + tx*4 + jj] = acc[i][jj];
}

// ---------------- end stage 2: combine partials, relu, 12x64 conv ----------------
__global__ __launch_bounds__(256) void k_end2(const float* __restrict__ out1, const float* __restrict__ b1,
                       const float* __restrict__ w2, const float* __restrict__ b2,
                       float* __restrict__ outp) {
    __shared__ float S[64][68];
    int n0 = blockIdx.x * 64, b = blockIdx.y;
    int t = threadIdx.x;
    for (int i = t; i < 4096; i += 256) {
        int o = i >> 6, n = i & 63;
        float s = b1[o];
        #pragma unroll
        for (int ks = 0; ks < 4; ks++)
            s += out1[(((size_t)ks*NB + b)*64 + o)*NN + n0 + n];
        S[o][n] = s > 0.f ? s : 0.f;
    }
    __syncthreads();
    for (int idx = t; idx < 12*64; idx += 256) {
        int jr = idx >> 6, n = idx & 63;
        float s = b2[jr];
        for (int o = 0; o < 64; o++) s += w2[jr*64 + o] * S[o][n];
        outp[((size_t)b*12 + jr)*NN + n0 + n] = s;
    }
}

extern "C" void kernel_launch(void* const* d_in, const int* in_sizes, int n_in,
                              void* d_out, int out_size, void* d_ws, size_t ws_size,
                              hipStream_t stream) {
    (void)in_sizes; (void)n_in; (void)out_size;
    if (ws_size < WS_FLOATS * sizeof(float)) return;

    const float* inputs  = (const float*)d_in[0];
    const int*   ind     = (const int*)  d_in[1];
    const float* start_w = (const float*)d_in[2];
    const float* start_b = (const float*)d_in[3];
    const float* starta_w= (const float*)d_in[4];
    const float* starta_b= (const float*)d_in[5];
    const float* p1      = (const float*)d_in[6];
    const float* p2      = (const float*)d_in[7];
    const float* p3      = (const float*)d_in[8];
    const float* pk      = (const float*)d_in[9];
    const float* fc1_w   = (const float*)d_in[10];
    const float* fc2_w   = (const float*)d_in[11];
    const float* skip_w  = (const float*)d_in[12];
    const float* skip_b  = (const float*)d_in[13];
    const float* gconv_w = (const float*)d_in[14];
    const float* gconv_b = (const float*)d_in[15];
    const float* bn_g    = (const float*)d_in[16];
    const float* bn_b    = (const float*)d_in[17];
    const float* bna_g   = (const float*)d_in[18];
    const float* bna_b   = (const float*)d_in[19];
    const float* end1_w  = (const float*)d_in[20];
    const float* end1_b  = (const float*)d_in[21];
    const float* end2_w  = (const float*)d_in[22];
    const float* end2_b  = (const float*)d_in[23];

    float* ws   = (float*)d_ws;
    float* tab  = ws + OFF_TAB;
    float* adpg = ws + OFF_ADP;
    float* Mg   = ws + OFF_M;
    float* src  = ws + OFF_SRC;
    float* temp = ws + OFF_TEMP;
    f16*   Ah   = (f16*)(ws + OFF_AH);
    f16*   xh   = (f16*)(ws + OFF_XH);
    f16*   xl   = (f16*)(ws + OFF_XL);
    f16*   h1h  = (f16*)(ws + OFF_H1H);
    f16*   h1l  = (f16*)(ws + OFF_H1L);
    float* out1 = ws + OFF_H2;
    float* x    = ws + OFF_X;
    float* skip = ws + OFF_SKIP;

    k_tables<<<1, 64, 0, stream>>>(bn_g, bna_g, bna_b, starta_w, starta_b, tab);
    k_startfc<<<(NB*NL*NN)/256, 256, 0, stream>>>(inputs, start_w, start_b, fc1_w, fc2_w,
                                                  skip_w, skip_b, x, xh, xl, skip);
    k_adp<<<NB, 256, 0, stream>>>(p1, ind, pk, p3, adpg, Mg);
    k_st<<<dim3(8, NB), 256, 0, stream>>>(p2, adpg, Mg, src, temp);
    k_A<<<dim3(136, 1, NB), 256, 0, stream>>>(src, temp, Ah);

    for (int i = 0; i < 7; i++) {            // layer 7's gemms/epilogue are dead code
        k_gmm<<<512, 256, 0, stream>>>(xh, xl, Ah, h1h, h1l);
        k_g2e<<<256, 256, 0, stream>>>(h1h, h1l, Ah, xh, xl, x, inputs,
                                       gconv_w, gconv_b, bn_b, tab,
                                       fc1_w, fc2_w, skip_w, skip_b, skip, i);
    }
    k_end1<<<dim3(16, 4, NB), 256, 0, stream>>>(skip, end1_w, out1);
    k_end2<<<dim3(16, NB), 256, 0, stream>>>(out1, end1_b, end2_w, end2_b, (float*)d_out);
}

// Round 6
// 929.897 us; speedup vs baseline: 1.1210x; 1.1210x over previous
//
#include <hip/hip_runtime.h>
#include <math.h>

#define NB 16
#define NCH 16
#define NL 13
#define NN 1024
#define NT 12
#define NLAY 8
#define MROWS 208          // NL*NCH valid rows (row = l*16 + c)
#define MPAD 256           // padded plane rows

typedef _Float16 f16;
typedef __attribute__((ext_vector_type(8))) _Float16 f16x8;
typedef __attribute__((ext_vector_type(16))) float f32x16;

// ---------------- workspace layout (float offsets) ----------------
#define OFF_TAB   0
#define OFF_ADP   1024
#define OFF_M     (OFF_ADP  + (size_t)NB*1024)
#define OFF_SRC   (OFF_M    + (size_t)NB*1024)
#define OFF_TEMP  (OFF_SRC  + (size_t)NB*NN*32)
#define OFF_AH    (OFF_TEMP + (size_t)NB*NN*32)                 // A f16 [b][1024][1024]
#define OFF_XH    (OFF_AH   + (size_t)NB*NN*NN/2)               // xs hi f16 [b][256][1024]
#define OFF_XL    (OFF_XH   + (size_t)NB*MPAD*NN/2)
#define OFF_H1H   (OFF_XL   + (size_t)NB*MPAD*NN/2)
#define OFF_H1L   (OFF_H1H  + (size_t)NB*MPAD*NN/2)
#define OFF_H2    (OFF_H1L  + (size_t)NB*MPAD*NN/2)             // out1 partials for end stage
#define OFF_X     (OFF_H2   + (size_t)NB*MPAD*NN)               // x f32 [b][208][1024]
#define OFF_SKIP  (OFF_X    + (size_t)NB*MROWS*NN)              // skip f32 [b][832][1024]
#define WS_FLOATS (OFF_SKIP + (size_t)NB*832*NN)

__device__ __forceinline__ void gload16(const void* g, void* l) {
    __builtin_amdgcn_global_load_lds(
        (const __attribute__((address_space(1))) unsigned int*)g,
        (__attribute__((address_space(3))) unsigned int*)l,
        16, 0, 0);
}

__device__ __forceinline__ float fast_tanh(float x) {
    float e = __expf(2.0f * x);
    return 1.0f - 2.0f / (e + 1.0f);
}

// ---------------- tables: bn scale + x_a affine recurrence ----------------
__global__ void k_tables(const float* __restrict__ bn_g,
                         const float* __restrict__ bna_g, const float* __restrict__ bna_b,
                         const float* __restrict__ sa_w, const float* __restrict__ sa_b,
                         float* __restrict__ tab) {
    int c = threadIdx.x;
    if (c >= 16) return;
    float inv = 1.0f / sqrtf(1.0f + 1e-5f);
    float A = sa_w[c], Bc = sa_b[c];
    for (int i = 0; i < NLAY; i++) {
        tab[i*16 + c]       = bn_g[i*16 + c] * inv;
        tab[128 + i*16 + c] = A;
        tab[256 + i*16 + c] = Bc;
        float ga = bna_g[i*16 + c] * inv;
        A  = 2.0f * ga * A;
        Bc = 2.0f * ga * Bc + bna_b[i*16 + c];
    }
}

// ---------------- start conv + fc layer 0 (row = l*16 + c) ----------------
__global__ __launch_bounds__(256) void k_startfc(const float* __restrict__ inp,
                        const float* __restrict__ sw, const float* __restrict__ sb,
                        const float* __restrict__ fc1, const float* __restrict__ fc2,
                        const float* __restrict__ skw, const float* __restrict__ skb,
                        float* __restrict__ x, f16* __restrict__ xh, f16* __restrict__ xl,
                        float* __restrict__ skip) {
    __shared__ float W1[256], W2[256], W3[128], B3[8], SW[16], SB[16];
    int t = threadIdx.x;
    if (t < 256) { W1[t] = fc1[t]; W2[t] = fc2[t]; }
    if (t < 128) W3[t] = skw[t];             // layer 0
    if (t < 8)   B3[t] = skb[t];
    if (t < 16)  { SW[t] = sw[t]; SB[t] = sb[t]; }
    __syncthreads();
    int idx = blockIdx.x*256 + t;            // over (b,l,n)
    int n = idx & 1023;
    int q = idx >> 10;
    int l = q % 13, b = q / 13;
    float u = (l == 0) ? 0.f : inp[((size_t)(b*2 + 0)*NN + n)*NT + (l - 1)];
    float v[16], t1[16], v2[16];
    #pragma unroll
    for (int c = 0; c < 16; c++) {
        v[c] = SW[c]*u + SB[c];
        x[((size_t)b*MROWS + l*16 + c)*NN + n] = v[c];
    }
    #pragma unroll
    for (int c = 0; c < 16; c++) {
        float s = 0.f;
        #pragma unroll
        for (int j = 0; j < 16; j++) s += W1[c*16 + j] * v[j];
        t1[c] = fmaxf(s, 0.f);
    }
    #pragma unroll
    for (int c = 0; c < 16; c++) {
        float s = 0.f;
        #pragma unroll
        for (int j = 0; j < 16; j++) s += W2[c*16 + j] * t1[j];
        float z = 2.f*s + v[c];
        v2[c] = 1.f / (1.f + __expf(-z));
        size_t o = ((size_t)b*MPAD + l*16 + c)*NN + n;
        f16 hi = (f16)v2[c];
        xh[o] = hi;
        xl[o] = (f16)(v2[c] - (float)hi);
    }
    #pragma unroll
    for (int sc = 0; sc < 8; sc++) {
        float s = B3[sc];
        #pragma unroll
        for (int c = 0; c < 16; c++) s += W3[sc*16 + c] * v2[c];
        skip[((size_t)b*832 + 7*104 + sc*13 + l)*NN + n] = s;
    }
}

// ---------------- adp / M (one block per batch, tiny) ----------------
__global__ __launch_bounds__(256) void k_adp(const float* __restrict__ p1, const int* __restrict__ ind,
                      const float* __restrict__ pk, const float* __restrict__ p3,
                      float* __restrict__ adpg, float* __restrict__ Mg) {
    __shared__ float te[32];
    __shared__ float adp[32][32];
    __shared__ float p3s[32][32];
    int b = blockIdx.x, t = threadIdx.x;
    if (t < 32) te[t] = p1[(size_t)ind[b]*32 + t];
    for (int i = t; i < 1024; i += 256) p3s[i >> 5][i & 31] = p3[i];
    __syncthreads();
    for (int i = t; i < 1024; i += 256) {
        float s = 0.f;
        for (int q = 0; q < 32; q++) s += te[q] * pk[q*1024 + i];
        adp[i >> 5][i & 31] = s;
        adpg[(size_t)b*1024 + i] = s;
    }
    __syncthreads();
    for (int i = t; i < 1024; i += 256) {
        int j = i >> 5, c = i & 31;
        float s = 0.f;
        for (int k = 0; k < 32; k++) s += adp[j][k] * p3s[c][k];
        Mg[(size_t)b*1024 + i] = s;
    }
}

// ---------------- src/temp: 8 blocks per batch ----------------
__global__ __launch_bounds__(256) void k_st(const float* __restrict__ p2, const float* __restrict__ adpg,
                     const float* __restrict__ Mg,
                     float* __restrict__ src, float* __restrict__ temp) {
    __shared__ float adpS[32][32], MS[32][32], p2S[128][32];
    int b = blockIdx.y, n0 = blockIdx.x * 128, t = threadIdx.x;
    for (int i = t; i < 1024; i += 256) {
        adpS[i >> 5][i & 31] = adpg[(size_t)b*1024 + i];
        MS[i >> 5][i & 31]   = Mg[(size_t)b*1024 + i];
    }
    for (int i = t; i < 128*32; i += 256) p2S[i >> 5][i & 31] = p2[(size_t)(n0 + (i >> 5))*32 + (i & 31)];
    __syncthreads();
    int k = t & 31, g = t >> 5;
    for (int nn = g; nn < 128; nn += 8) {
        float rs = 0.f, rt = 0.f;
        #pragma unroll 8
        for (int j = 0; j < 32; j++) {
            float pv = p2S[nn][j];
            rs += pv * adpS[j][k];
            rt += pv * MS[j][k];
        }
        src [((size_t)b*NN + n0 + nn)*32 + k] = rs;
        temp[((size_t)b*NN + n0 + nn)*32 + k] = rt;
    }
}

// ---------------- A tiles: triangular grid, transposed-LDS float4 dots ----------------
__global__ __launch_bounds__(256) void k_A(const float* __restrict__ src, const float* __restrict__ temp,
                    f16* __restrict__ Amat) {
    int b = blockIdx.z;
    int r = blockIdx.x, ti = 0;
    while (r >= 16 - ti) { r -= 16 - ti; ti++; }
    int tj = ti + r;
    int n0 = ti*64, m0 = tj*64;
    __shared__ float snT[32][68], tmT[32][68], smT[32][68], tnT[32][68];
    __shared__ f16 At[64][72];
    int t = threadIdx.x;
    const float* sb_ = src  + (size_t)b*NN*32;
    const float* tb_ = temp + (size_t)b*NN*32;
    for (int i = t; i < 64*32; i += 256) {
        int rr = i >> 5, k = i & 31;
        snT[k][rr] = sb_[(n0 + rr)*32 + k];
        tmT[k][rr] = tb_[(m0 + rr)*32 + k];
        smT[k][rr] = sb_[(m0 + rr)*32 + k];
        tnT[k][rr] = tb_[(n0 + rr)*32 + k];
    }
    __syncthreads();
    int tr = (t >> 4) * 4, tc = (t & 15) * 4;
    float acc1[4][4] = {}, acc2[4][4] = {};
    #pragma unroll 4
    for (int k = 0; k < 32; k++) {
        float4 a  = *(const float4*)&snT[k][tr];
        float4 bb = *(const float4*)&tmT[k][tc];
        float4 c2 = *(const float4*)&smT[k][tc];
        float4 d2 = *(const float4*)&tnT[k][tr];
        float av[4] = {a.x, a.y, a.z, a.w};
        float bv[4] = {bb.x, bb.y, bb.z, bb.w};
        float cv[4] = {c2.x, c2.y, c2.z, c2.w};
        float dv[4] = {d2.x, d2.y, d2.z, d2.w};
        #pragma unroll
        for (int i = 0; i < 4; i++)
            #pragma unroll
            for (int jj = 0; jj < 4; jj++) { acc1[i][jj] += av[i]*bv[jj]; acc2[i][jj] += cv[jj]*dv[i]; }
    }
    #pragma unroll
    for (int i = 0; i < 4; i++)
        #pragma unroll
        for (int jj = 0; jj < 4; jj++) {
            float v = fast_tanh(acc1[i][jj] - acc2[i][jj]);
            Amat[((size_t)b*NN + n0 + tr + i)*NN + m0 + tc + jj] = (f16)(v > 0.f ? v : 0.f);
            At[tc + jj][tr + i] = (f16)(-v > 0.f ? -v : 0.f);
        }
    __syncthreads();
    for (int i = t; i < 512; i += 256) {
        int rr = i >> 3, c8 = (i & 7) * 8;
        f16* dst = &Amat[((size_t)b*NN + m0 + rr)*NN + n0 + c8];
        #pragma unroll
        for (int k = 0; k < 8; k++) dst[k] = At[rr][c8 + k];
    }
}

// ---------------- hop1 MFMA GEMM: h1 = (Xh+Xl)·A^T ----------------
__global__ __launch_bounds__(256) void k_gmm(const f16* __restrict__ Xh, const f16* __restrict__ Xl,
                     const f16* __restrict__ Ag, f16* __restrict__ Ch, f16* __restrict__ Cl) {
    __shared__ alignas(16) f16 As[2][128*64];
    __shared__ alignas(16) f16 Xs[2][2*64*64];
    const int bid = blockIdx.x;                // 0..511
    const int xcd = bid & 7;
    const int j   = bid >> 3;
    const int b   = xcd + ((j >> 5) << 3);
    const int tile = j & 31;
    const int my  = tile >> 3;
    const int n0  = (tile & 7) * 128;
    const int t = threadIdx.x;
    const int w = t >> 6, lane = t & 63;
    const char* Ab  = (const char*)(Ag + (size_t)b*NN*NN);
    const char* Xhb = (const char*)(Xh + (size_t)b*MPAD*NN);
    const char* Xlb = (const char*)(Xl + (size_t)b*MPAD*NN);

    const char* asrc[4];
    int adst[4];
    const char* xsrc[4];
    int xdst[4];
    {
        const char* Abase = Ab + (size_t)n0*2048;
        const char* Xb0 = Xhb + (size_t)(my*64)*2048;
        const char* Xb1 = Xlb + (size_t)(my*64)*2048;
        #pragma unroll
        for (int rr = 0; rr < 4; ++rr) {
            int q = rr*4 + w;
            int slot = q*64 + lane;
            int row = slot >> 3, ch = slot & 7;
            asrc[rr] = Abase + (size_t)row*2048 + ((ch ^ (row & 7)) << 4);
            adst[rr] = q*1024;
            int xrow = row & 63;
            xsrc[rr] = ((q >> 3) ? Xb1 : Xb0) + (size_t)xrow*2048 + ((ch ^ (xrow & 7)) << 4);
            xdst[rr] = q*1024;
        }
    }

    const int wm = (w >> 1) * 32, wn = (w & 1) * 64;
    const int kh = lane >> 5;
    const int arow = wm + (lane & 31);
    const int brow0 = wn + (lane & 31);
    const int brow1 = brow0 + 32;
    const int swa = arow & 7, swb0 = brow0 & 7, swb1 = brow1 & 7;

    f32x16 acc0 = {}, acc1 = {};

    auto stage = [&](int buf, int it) {
        size_t koff = (size_t)it * 128;
        #pragma unroll
        for (int rr = 0; rr < 4; ++rr)
            gload16(asrc[rr] + koff, (char*)As[buf] + adst[rr]);
        #pragma unroll
        for (int rr = 0; rr < 4; ++rr)
            gload16(xsrc[rr] + koff, (char*)Xs[buf] + xdst[rr]);
    };
    auto compute = [&](int buf) {
        const char* aP0 = (const char*)Xs[buf] + (size_t)arow*128;
        const char* aP1 = aP0 + 8192;
        const char* bP0 = (const char*)As[buf] + (size_t)brow0*128;
        const char* bP1 = (const char*)As[buf] + (size_t)brow1*128;
        #pragma unroll
        for (int s = 0; s < 4; ++s) {
            int cn = s*2 + kh;
            f16x8 ah = *(const f16x8*)(aP0 + ((cn ^ swa) << 4));
            f16x8 al = *(const f16x8*)(aP1 + ((cn ^ swa) << 4));
            f16x8 b0 = *(const f16x8*)(bP0 + ((cn ^ swb0) << 4));
            f16x8 b1 = *(const f16x8*)(bP1 + ((cn ^ swb1) << 4));
            acc0 = __builtin_amdgcn_mfma_f32_32x32x16_f16(ah, b0, acc0, 0, 0, 0);
            acc1 = __builtin_amdgcn_mfma_f32_32x32x16_f16(ah, b1, acc1, 0, 0, 0);
            acc0 = __builtin_amdgcn_mfma_f32_32x32x16_f16(al, b0, acc0, 0, 0, 0);
            acc1 = __builtin_amdgcn_mfma_f32_32x32x16_f16(al, b1, acc1, 0, 0, 0);
        }
    };

    stage(0, 0);
    int cur = 0;
    for (int it = 0; it < 15; ++it) {
        stage(cur ^ 1, it + 1);
        asm volatile("s_waitcnt vmcnt(8)" ::: "memory");
        __builtin_amdgcn_s_barrier();
        compute(cur);
        __builtin_amdgcn_s_barrier();
        cur ^= 1;
    }
    asm volatile("s_waitcnt vmcnt(0)" ::: "memory");
    __builtin_amdgcn_s_barrier();
    compute(cur);

    const int coll = lane & 31;
    #pragma unroll
    for (int reg = 0; reg < 16; ++reg) {
        int m = my*64 + wm + (reg & 3) + 8*(reg >> 2) + 4*kh;
        if (m < MROWS) {
            size_t o0 = ((size_t)b*MPAD + m)*NN + n0 + wn + coll;
            float v0 = acc0[reg], v1 = acc1[reg];
            f16 h0 = (f16)v0; Ch[o0]      = h0; Cl[o0]      = (f16)(v0 - (float)h0);
            f16 h1 = (f16)v1; Ch[o0 + 32] = h1; Cl[o0 + 32] = (f16)(v1 - (float)h1);
        }
    }
}

// ---------------- hop2 GEMM + fused epilogue (same geometry as k_gmm) ----------------
// Block = 64M x 128N of h2; M rows = l*16+c so the block holds all 16 channels
// for 4 consecutive l values -> epilogue is block-local. h2 never hits HBM.
__global__ __launch_bounds__(256) void k_g2e(
        const f16* __restrict__ h1h, const f16* __restrict__ h1l,
        const f16* __restrict__ Ag,
        f16* __restrict__ xh, f16* __restrict__ xl,
        float* __restrict__ x, const float* __restrict__ inp,
        const float* __restrict__ gw, const float* __restrict__ gb,
        const float* __restrict__ bnb, const float* __restrict__ tab,
        const float* __restrict__ fc1, const float* __restrict__ fc2,
        const float* __restrict__ skw, const float* __restrict__ skb,
        float* __restrict__ skip, int layer) {
    __shared__ alignas(16) f16 As[2][128*64];     // 32 KB; reused as H2 f32[64][128] at tail
    __shared__ alignas(16) f16 Xs[2][2*64*64];    // 32 KB
    __shared__ float Wg[768], W1s[256], W2s[256], W3s[128], B3s[8];
    __shared__ float GBs[16], BNBs[16], BNSs[16], ACs[16], BCs[16];
    const int bid = blockIdx.x;                // 0..511
    const int xcd = bid & 7;
    const int j   = bid >> 3;
    const int b   = xcd + ((j >> 5) << 3);
    const int tile = j & 31;
    const int my  = tile >> 3;
    const int n0  = (tile & 7) * 128;
    const int t = threadIdx.x;
    const int w = t >> 6, lane = t & 63;
    const int nl = layer + 1;
    const char* Ab  = (const char*)(Ag  + (size_t)b*NN*NN);
    const char* Xhb = (const char*)(h1h + (size_t)b*MPAD*NN);
    const char* Xlb = (const char*)(h1l + (size_t)b*MPAD*NN);

    const char* asrc[4];
    int adst[4];
    const char* xsrc[4];
    int xdst[4];
    {
        const char* Abase = Ab + (size_t)n0*2048;
        const char* Xb0 = Xhb + (size_t)(my*64)*2048;
        const char* Xb1 = Xlb + (size_t)(my*64)*2048;
        #pragma unroll
        for (int rr = 0; rr < 4; ++rr) {
            int q = rr*4 + w;
            int slot = q*64 + lane;
            int row = slot >> 3, ch = slot & 7;
            asrc[rr] = Abase + (size_t)row*2048 + ((ch ^ (row & 7)) << 4);
            adst[rr] = q*1024;
            int xrow = row & 63;
            xsrc[rr] = ((q >> 3) ? Xb1 : Xb0) + (size_t)xrow*2048 + ((ch ^ (xrow & 7)) << 4);
            xdst[rr] = q*1024;
        }
    }

    const int wm = (w >> 1) * 32, wn = (w & 1) * 64;
    const int kh = lane >> 5;
    const int arow = wm + (lane & 31);
    const int brow0 = wn + (lane & 31);
    const int brow1 = brow0 + 32;
    const int swa = arow & 7, swb0 = brow0 & 7, swb1 = brow1 & 7;

    f32x16 acc0 = {}, acc1 = {};

    auto stage = [&](int buf, int it) {
        size_t koff = (size_t)it * 128;
        #pragma unroll
        for (int rr = 0; rr < 4; ++rr)
            gload16(asrc[rr] + koff, (char*)As[buf] + adst[rr]);
        #pragma unroll
        for (int rr = 0; rr < 4; ++rr)
            gload16(xsrc[rr] + koff, (char*)Xs[buf] + xdst[rr]);
    };
    auto compute = [&](int buf) {
        const char* aP0 = (const char*)Xs[buf] + (size_t)arow*128;
        const char* aP1 = aP0 + 8192;
        const char* bP0 = (const char*)As[buf] + (size_t)brow0*128;
        const char* bP1 = (const char*)As[buf] + (size_t)brow1*128;
        #pragma unroll
        for (int s = 0; s < 4; ++s) {
            int cn = s*2 + kh;
            f16x8 ah = *(const f16x8*)(aP0 + ((cn ^ swa) << 4));
            f16x8 al = *(const f16x8*)(aP1 + ((cn ^ swa) << 4));
            f16x8 b0 = *(const f16x8*)(bP0 + ((cn ^ swb0) << 4));
            f16x8 b1 = *(const f16x8*)(bP1 + ((cn ^ swb1) << 4));
            acc0 = __builtin_amdgcn_mfma_f32_32x32x16_f16(ah, b0, acc0, 0, 0, 0);
            acc1 = __builtin_amdgcn_mfma_f32_32x32x16_f16(ah, b1, acc1, 0, 0, 0);
            acc0 = __builtin_amdgcn_mfma_f32_32x32x16_f16(al, b0, acc0, 0, 0, 0);
            acc1 = __builtin_amdgcn_mfma_f32_32x32x16_f16(al, b1, acc1, 0, 0, 0);
        }
    };

    stage(0, 0);
    // weights -> LDS (prologue only; compiler-inserted waits drain these loads)
    for (int i = t; i < 768; i += 256) Wg[i] = gw[layer*768 + i];
    if (t < 256) { W1s[t] = fc1[t]; W2s[t] = fc2[t]; }
    if (t < 128) W3s[t] = skw[nl*128 + t];
    if (t < 8)   B3s[t] = skb[nl*8 + t];
    if (t < 16) {
        GBs[t]  = gb[layer*16 + t];
        BNBs[t] = bnb[layer*16 + t];
        BNSs[t] = tab[layer*16 + t];
        ACs[t]  = tab[128 + layer*16 + t];
        BCs[t]  = tab[256 + layer*16 + t];
    }

    int cur = 0;
    for (int it = 0; it < 15; ++it) {
        stage(cur ^ 1, it + 1);
        asm volatile("s_waitcnt vmcnt(8)" ::: "memory");
        __builtin_amdgcn_s_barrier();
        compute(cur);
        __builtin_amdgcn_s_barrier();
        cur ^= 1;
    }
    asm volatile("s_waitcnt vmcnt(0)" ::: "memory");
    __builtin_amdgcn_s_barrier();
    compute(cur);
    __syncthreads();                                // all waves done reading stage LDS

    // acc -> LDS H2 f32 [64][128] (aliases As)
    float* H2 = (float*)&As[0][0];
    const int coll = lane & 31;
    #pragma unroll
    for (int reg = 0; reg < 16; ++reg) {
        int m = wm + (reg & 3) + 8*(reg >> 2) + 4*kh;
        H2[m*128 + wn + coll]      = acc0[reg];
        H2[m*128 + wn + coll + 32] = acc1[reg];
    }
    __syncthreads();

    // epilogue: 4 l-values x 128 n positions, all channels block-local
    const int lbase = my*4;
    for (int pos = t; pos < 512; pos += 256) {
        int lo = pos >> 7;
        int l = lbase + lo;
        if (l >= NL) continue;
        int n = pos & 127;
        int gn = n0 + n;
        float u1 = (l == 0) ? 0.f : inp[((size_t)(b*2 + 1)*NN + gn)*NT + (l - 1)];
        float vx[16], v1[16], v2[16], xnew[16];
        #pragma unroll
        for (int c = 0; c < 16; c++) {
            size_t op = ((size_t)b*MPAD + l*16 + c)*NN + gn;
            vx[c] = (float)xh[op] + (float)xl[op];
            v1[c] = (float)h1h[op] + (float)h1l[op];
            v2[c] = H2[(lo*16 + c)*128 + n];
        }
        #pragma unroll
        for (int o = 0; o < 16; o++) {
            float s = GBs[o];
            #pragma unroll
            for (int c = 0; c < 16; c++) s += Wg[o*48 + c]      * vx[c];
            #pragma unroll
            for (int c = 0; c < 16; c++) s += Wg[o*48 + 16 + c] * v1[c];
            #pragma unroll
            for (int c = 0; c < 16; c++) s += Wg[o*48 + 32 + c] * v2[c];
            float xa = ACs[o]*u1 + BCs[o];
            float vo = x[((size_t)b*MROWS + l*16 + o)*NN + gn];
            xnew[o] = BNSs[o]*(s + xa + vo) + BNBs[o];
        }
        if (layer < 6) {
            #pragma unroll
            for (int o = 0; o < 16; o++)
                x[((size_t)b*MROWS + l*16 + o)*NN + gn] = xnew[o];
        }
        float t1[16], vs[16];
        #pragma unroll
        for (int c = 0; c < 16; c++) {
            float s = 0.f;
            #pragma unroll
            for (int jq = 0; jq < 16; jq++) s += W1s[c*16 + jq] * xnew[jq];
            t1[c] = fmaxf(s, 0.f);
        }
        #pragma unroll
        for (int c = 0; c < 16; c++) {
            float s = 0.f;
            #pragma unroll
            for (int jq = 0; jq < 16; jq++) s += W2s[c*16 + jq] * t1[jq];
            float z = 2.f*s + xnew[c];
            vs[c] = 1.f / (1.f + __expf(-z));
            if (layer < 6) {
                size_t o = ((size_t)b*MPAD + l*16 + c)*NN + gn;
                f16 hi = (f16)vs[c];
                xh[o] = hi;
                xl[o] = (f16)(vs[c] - (float)hi);
            }
        }
        #pragma unroll
        for (int sc = 0; sc < 8; sc++) {
            float s = B3s[sc];
            #pragma unroll
            for (int c = 0; c < 16; c++) s += W3s[sc*16 + c] * vs[c];
            skip[((size_t)b*832 + (7 - nl)*104 + sc*13 + l)*NN + gn] = s;
        }
    }
}

// ---------------- end stage 1: split-K partial GEMM ----------------
__global__ __launch_bounds__(256) void k_end1(const float* __restrict__ skip, const float* __restrict__ w1,
                       float* __restrict__ out1) {
    __shared__ alignas(16) float Ws[52][68];
    __shared__ alignas(16) float Ss[52][68];
    int n0 = blockIdx.x * 64, ks = blockIdx.y, b = blockIdx.z;
    int t = threadIdx.x, ty = t >> 4, tx = t & 15;
    float acc[4][4] = {};
    int kbase = ks * 208;
    for (int kk = 0; kk < 4; kk++) {
        int k0 = kbase + kk*52;
        for (int i = t; i < 52*64; i += 256) {
            int r = i >> 6, c = i & 63;
            float sv = skip[((size_t)b*832 + k0 + r)*NN + n0 + c];
            Ss[r][c] = sv > 0.f ? sv : 0.f;
            Ws[r][c] = w1[(size_t)c*832 + k0 + r];
        }
        __syncthreads();
        #pragma unroll 4
        for (int k = 0; k < 52; k++) {
            float4 av = *(const float4*)&Ws[k][ty*4];
            float4 bv = *(const float4*)&Ss[k][tx*4];
            float a[4] = {av.x, av.y, av.z, av.w};
            float bb[4] = {bv.x, bv.y, bv.z, bv.w};
            #pragma unroll
            for (int i = 0; i < 4; i++)
                #pragma unroll
                for (int jj = 0; jj < 4; jj++) acc[i][jj] += a[i]*bb[jj];
        }
        __syncthreads();
    }
    #pragma unroll
    for (int i = 0; i < 4; i++)
        #pragma unroll
        for (int jj = 0; jj < 4; jj++)
            out1[(((size_t)ks*NB + b)*64 + ty*4 + i)*NN + n0 + tx*4 + jj] = acc[i][jj];
}

// ---------------- end stage 2: combine partials, relu, 12x64 conv ----------------
__global__ __launch_bounds__(256) void k_end2(const float* __restrict__ out1, const float* __restrict__ b1,
                       const float* __restrict__ w2, const float* __restrict__ b2,
                       float* __restrict__ outp) {
    __shared__ float S[64][68];
    int n0 = blockIdx.x * 64, b = blockIdx.y;
    int t = threadIdx.x;
    for (int i = t; i < 4096; i += 256) {
        int o = i >> 6, n = i & 63;
        float s = b1[o];
        #pragma unroll
        for (int ks = 0; ks < 4; ks++)
            s += out1[(((size_t)ks*NB + b)*64 + o)*NN + n0 + n];
        S[o][n] = s > 0.f ? s : 0.f;
    }
    __syncthreads();
    for (int idx = t; idx < 12*64; idx += 256) {
        int jr = idx >> 6, n = idx & 63;
        float s = b2[jr];
        for (int o = 0; o < 64; o++) s += w2[jr*64 + o] * S[o][n];
        outp[((size_t)b*12 + jr)*NN + n0 + n] = s;
    }
}

extern "C" void kernel_launch(void* const* d_in, const int* in_sizes, int n_in,
                              void* d_out, int out_size, void* d_ws, size_t ws_size,
                              hipStream_t stream) {
    (void)in_sizes; (void)n_in; (void)out_size;
    if (ws_size < WS_FLOATS * sizeof(float)) return;

    const float* inputs  = (const float*)d_in[0];
    const int*   ind     = (const int*)  d_in[1];
    const float* start_w = (const float*)d_in[2];
    const float* start_b = (const float*)d_in[3];
    const float* starta_w= (const float*)d_in[4];
    const float* starta_b= (const float*)d_in[5];
    const float* p1      = (const float*)d_in[6];
    const float* p2      = (const float*)d_in[7];
    const float* p3      = (const float*)d_in[8];
    const float* pk      = (const float*)d_in[9];
    const float* fc1_w   = (const float*)d_in[10];
    const float* fc2_w   = (const float*)d_in[11];
    const float* skip_w  = (const float*)d_in[12];
    const float* skip_b  = (const float*)d_in[13];
    const float* gconv_w = (const float*)d_in[14];
    const float* gconv_b = (const float*)d_in[15];
    const float* bn_g    = (const float*)d_in[16];
    const float* bn_b    = (const float*)d_in[17];
    const float* bna_g   = (const float*)d_in[18];
    const float* bna_b   = (const float*)d_in[19];
    const float* end1_w  = (const float*)d_in[20];
    const float* end1_b  = (const float*)d_in[21];
    const float* end2_w  = (const float*)d_in[22];
    const float* end2_b  = (const float*)d_in[23];

    float* ws   = (float*)d_ws;
    float* tab  = ws + OFF_TAB;
    float* adpg = ws + OFF_ADP;
    float* Mg   = ws + OFF_M;
    float* src  = ws + OFF_SRC;
    float* temp = ws + OFF_TEMP;
    f16*   Ah   = (f16*)(ws + OFF_AH);
    f16*   xh   = (f16*)(ws + OFF_XH);
    f16*   xl   = (f16*)(ws + OFF_XL);
    f16*   h1h  = (f16*)(ws + OFF_H1H);
    f16*   h1l  = (f16*)(ws + OFF_H1L);
    float* out1 = ws + OFF_H2;
    float* x    = ws + OFF_X;
    float* skip = ws + OFF_SKIP;

    k_tables<<<1, 64, 0, stream>>>(bn_g, bna_g, bna_b, starta_w, starta_b, tab);
    k_startfc<<<(NB*NL*NN)/256, 256, 0, stream>>>(inputs, start_w, start_b, fc1_w, fc2_w,
                                                  skip_w, skip_b, x, xh, xl, skip);
    k_adp<<<NB, 256, 0, stream>>>(p1, ind, pk, p3, adpg, Mg);
    k_st<<<dim3(8, NB), 256, 0, stream>>>(p2, adpg, Mg, src, temp);
    k_A<<<dim3(136, 1, NB), 256, 0, stream>>>(src, temp, Ah);

    for (int i = 0; i < 7; i++) {            // layer 7's gemms/epilogue are dead code
        k_gmm<<<512, 256, 0, stream>>>(xh, xl, Ah, h1h, h1l);
        k_g2e<<<512, 256, 0, stream>>>(h1h, h1l, Ah, xh, xl, x, inputs,
                                       gconv_w, gconv_b, bn_b, tab,
                                       fc1_w, fc2_w, skip_w, skip_b, skip, i);
    }
    k_end1<<<dim3(16, 4, NB), 256, 0, stream>>>(skip, end1_w, out1);
    k_end2<<<dim3(16, NB), 256, 0, stream>>>(out1, end1_b, end2_w, end2_b, (float*)d_out);
}

// Round 7
// 619.281 us; speedup vs baseline: 1.6833x; 1.5016x over previous
//
#include <hip/hip_runtime.h>
#include <math.h>

#define NB 16
#define NCH 16
#define NL 13
#define NN 1024
#define NT 12
#define NLAY 8
#define MROWS 208          // NCH*NL valid rows
#define MPAD 256           // padded plane rows

typedef _Float16 f16;
typedef __attribute__((ext_vector_type(8))) _Float16 f16x8;
typedef __attribute__((ext_vector_type(16))) float f32x16;

// ---------------- workspace layout (float offsets) ----------------
#define OFF_TAB   0
#define OFF_ADP   1024
#define OFF_M     (OFF_ADP  + (size_t)NB*1024)
#define OFF_SRC   (OFF_M    + (size_t)NB*1024)
#define OFF_TEMP  (OFF_SRC  + (size_t)NB*NN*32)
#define OFF_AH    (OFF_TEMP + (size_t)NB*NN*32)                 // A f16 [b][1024][1024]
#define OFF_XH    (OFF_AH   + (size_t)NB*NN*NN/2)               // xs hi f16 [b][256][1024]
#define OFF_XL    (OFF_XH   + (size_t)NB*MPAD*NN/2)
#define OFF_H1H   (OFF_XL   + (size_t)NB*MPAD*NN/2)
#define OFF_H1L   (OFF_H1H  + (size_t)NB*MPAD*NN/2)
#define OFF_H2    (OFF_H1L  + (size_t)NB*MPAD*NN/2)             // h2 f32; reused as out1 partials
#define OFF_X     (OFF_H2   + (size_t)NB*MPAD*NN)               // x f32 [b][208][1024]
#define OFF_SKIP  (OFF_X    + (size_t)NB*MROWS*NN)              // skip f32 [b][832][1024]
#define WS_FLOATS (OFF_SKIP + (size_t)NB*832*NN)

__device__ __forceinline__ void gload16(const void* g, void* l) {
    __builtin_amdgcn_global_load_lds(
        (const __attribute__((address_space(1))) unsigned int*)g,
        (__attribute__((address_space(3))) unsigned int*)l,
        16, 0, 0);
}

__device__ __forceinline__ float fast_tanh(float x) {
    float e = __expf(2.0f * x);
    return 1.0f - 2.0f / (e + 1.0f);
}

// ---------------- tables: bn scale + x_a affine recurrence ----------------
__global__ void k_tables(const float* __restrict__ bn_g,
                         const float* __restrict__ bna_g, const float* __restrict__ bna_b,
                         const float* __restrict__ sa_w, const float* __restrict__ sa_b,
                         float* __restrict__ tab) {
    int c = threadIdx.x;
    if (c >= 16) return;
    float inv = 1.0f / sqrtf(1.0f + 1e-5f);
    float A = sa_w[c], Bc = sa_b[c];
    for (int i = 0; i < NLAY; i++) {
        tab[i*16 + c]       = bn_g[i*16 + c] * inv;
        tab[128 + i*16 + c] = A;
        tab[256 + i*16 + c] = Bc;
        float ga = bna_g[i*16 + c] * inv;
        A  = 2.0f * ga * A;
        Bc = 2.0f * ga * Bc + bna_b[i*16 + c];
    }
}

// ---------------- start conv + fc layer 0 (weights via uniform s_load) ----------------
__global__ __launch_bounds__(256) void k_startfc(const float* __restrict__ inp,
                        const float* __restrict__ sw, const float* __restrict__ sb,
                        const float* __restrict__ fc1, const float* __restrict__ fc2,
                        const float* __restrict__ skw, const float* __restrict__ skb,
                        float* __restrict__ x, f16* __restrict__ xh, f16* __restrict__ xl,
                        float* __restrict__ skip) {
    int t = threadIdx.x;
    int idx = blockIdx.x*256 + t;            // over (b,l,n)
    int n = idx & 1023;
    int q = idx >> 10;
    int l = q % 13, b = q / 13;
    float u = (l == 0) ? 0.f : inp[((size_t)(b*2 + 0)*NN + n)*NT + (l - 1)];
    float v[16], t1[16], v2[16];
    #pragma unroll
    for (int c = 0; c < 16; c++) {
        v[c] = sw[c]*u + sb[c];
        x[((size_t)b*MROWS + c*13 + l)*NN + n] = v[c];
    }
    #pragma unroll
    for (int c = 0; c < 16; c++) {
        float s = 0.f;
        #pragma unroll
        for (int j = 0; j < 16; j++) s += fc1[c*16 + j] * v[j];
        t1[c] = fmaxf(s, 0.f);
    }
    #pragma unroll
    for (int c = 0; c < 16; c++) {
        float s = 0.f;
        #pragma unroll
        for (int j = 0; j < 16; j++) s += fc2[c*16 + j] * t1[j];
        float z = 2.f*s + v[c];
        v2[c] = 1.f / (1.f + __expf(-z));
        size_t o = ((size_t)b*MPAD + c*13 + l)*NN + n;
        f16 hi = (f16)v2[c];
        xh[o] = hi;
        xl[o] = (f16)(v2[c] - (float)hi);
    }
    #pragma unroll
    for (int sc = 0; sc < 8; sc++) {
        float s = skb[sc];
        #pragma unroll
        for (int c = 0; c < 16; c++) s += skw[sc*16 + c] * v2[c];
        skip[((size_t)b*832 + 7*104 + sc*13 + l)*NN + n] = s;
    }
}

// ---------------- adp / M (one block per batch, tiny) ----------------
__global__ __launch_bounds__(256) void k_adp(const float* __restrict__ p1, const int* __restrict__ ind,
                      const float* __restrict__ pk, const float* __restrict__ p3,
                      float* __restrict__ adpg, float* __restrict__ Mg) {
    __shared__ float te[32];
    __shared__ float adp[32][32];
    __shared__ float p3s[32][32];
    int b = blockIdx.x, t = threadIdx.x;
    if (t < 32) te[t] = p1[(size_t)ind[b]*32 + t];
    for (int i = t; i < 1024; i += 256) p3s[i >> 5][i & 31] = p3[i];
    __syncthreads();
    for (int i = t; i < 1024; i += 256) {
        float s = 0.f;
        for (int q = 0; q < 32; q++) s += te[q] * pk[q*1024 + i];
        adp[i >> 5][i & 31] = s;
        adpg[(size_t)b*1024 + i] = s;
    }
    __syncthreads();
    for (int i = t; i < 1024; i += 256) {
        int j = i >> 5, c = i & 31;
        float s = 0.f;
        for (int k = 0; k < 32; k++) s += adp[j][k] * p3s[c][k];
        Mg[(size_t)b*1024 + i] = s;
    }
}

// ---------------- src/temp: 8 blocks per batch ----------------
__global__ __launch_bounds__(256) void k_st(const float* __restrict__ p2, const float* __restrict__ adpg,
                     const float* __restrict__ Mg,
                     float* __restrict__ src, float* __restrict__ temp) {
    __shared__ float adpS[32][32], MS[32][32], p2S[128][32];
    int b = blockIdx.y, n0 = blockIdx.x * 128, t = threadIdx.x;
    for (int i = t; i < 1024; i += 256) {
        adpS[i >> 5][i & 31] = adpg[(size_t)b*1024 + i];
        MS[i >> 5][i & 31]   = Mg[(size_t)b*1024 + i];
    }
    for (int i = t; i < 128*32; i += 256) p2S[i >> 5][i & 31] = p2[(size_t)(n0 + (i >> 5))*32 + (i & 31)];
    __syncthreads();
    int k = t & 31, g = t >> 5;
    for (int nn = g; nn < 128; nn += 8) {
        float rs = 0.f, rt = 0.f;
        #pragma unroll 8
        for (int j = 0; j < 32; j++) {
            float pv = p2S[nn][j];
            rs += pv * adpS[j][k];
            rt += pv * MS[j][k];
        }
        src [((size_t)b*NN + n0 + nn)*32 + k] = rs;
        temp[((size_t)b*NN + n0 + nn)*32 + k] = rt;
    }
}

// ---------------- A tiles: triangular grid, transposed-LDS float4 dots ----------------
__global__ __launch_bounds__(256) void k_A(const float* __restrict__ src, const float* __restrict__ temp,
                    f16* __restrict__ Amat) {
    int b = blockIdx.z;
    int r = blockIdx.x, ti = 0;
    while (r >= 16 - ti) { r -= 16 - ti; ti++; }
    int tj = ti + r;
    int n0 = ti*64, m0 = tj*64;
    __shared__ float snT[32][68], tmT[32][68], smT[32][68], tnT[32][68];
    __shared__ f16 At[64][72];
    int t = threadIdx.x;
    const float* sb_ = src  + (size_t)b*NN*32;
    const float* tb_ = temp + (size_t)b*NN*32;
    for (int i = t; i < 64*32; i += 256) {
        int rr = i >> 5, k = i & 31;
        snT[k][rr] = sb_[(n0 + rr)*32 + k];
        tmT[k][rr] = tb_[(m0 + rr)*32 + k];
        smT[k][rr] = sb_[(m0 + rr)*32 + k];
        tnT[k][rr] = tb_[(n0 + rr)*32 + k];
    }
    __syncthreads();
    int tr = (t >> 4) * 4, tc = (t & 15) * 4;
    float acc1[4][4] = {}, acc2[4][4] = {};
    #pragma unroll 4
    for (int k = 0; k < 32; k++) {
        float4 a  = *(const float4*)&snT[k][tr];
        float4 bb = *(const float4*)&tmT[k][tc];
        float4 c2 = *(const float4*)&smT[k][tc];
        float4 d2 = *(const float4*)&tnT[k][tr];
        float av[4] = {a.x, a.y, a.z, a.w};
        float bv[4] = {bb.x, bb.y, bb.z, bb.w};
        float cv[4] = {c2.x, c2.y, c2.z, c2.w};
        float dv[4] = {d2.x, d2.y, d2.z, d2.w};
        #pragma unroll
        for (int i = 0; i < 4; i++)
            #pragma unroll
            for (int jj = 0; jj < 4; jj++) { acc1[i][jj] += av[i]*bv[jj]; acc2[i][jj] += cv[jj]*dv[i]; }
    }
    #pragma unroll
    for (int i = 0; i < 4; i++)
        #pragma unroll
        for (int jj = 0; jj < 4; jj++) {
            float v = fast_tanh(acc1[i][jj] - acc2[i][jj]);
            Amat[((size_t)b*NN + n0 + tr + i)*NN + m0 + tc + jj] = (f16)(v > 0.f ? v : 0.f);
            At[tc + jj][tr + i] = (f16)(-v > 0.f ? -v : 0.f);
        }
    __syncthreads();
    for (int i = t; i < 512; i += 256) {
        int rr = i >> 3, c8 = (i & 7) * 8;
        f16* dst = &Amat[((size_t)b*NN + m0 + rr)*NN + n0 + c8];
        #pragma unroll
        for (int k = 0; k < 8; k++) dst[k] = At[rr][c8 + k];
    }
}

// ---------------- MFMA GEMM, 2-phase double-buffered pipeline ----------------
template<bool HOP1>
__global__ __launch_bounds__(256) void k_gmm(const f16* __restrict__ Xh, const f16* __restrict__ Xl,
                     const f16* __restrict__ Ag, float* __restrict__ Cf,
                     f16* __restrict__ Ch, f16* __restrict__ Cl) {
    __shared__ alignas(16) f16 As[2][128*64];
    __shared__ alignas(16) f16 Xs[2][2*64*64];
    const int bid = blockIdx.x;                // 0..511
    const int xcd = bid & 7;
    const int j   = bid >> 3;
    const int b   = xcd + ((j >> 5) << 3);
    const int tile = j & 31;
    const int my  = tile >> 3;
    const int n0  = (tile & 7) * 128;
    const int t = threadIdx.x;
    const int w = t >> 6, lane = t & 63;
    const char* Ab  = (const char*)(Ag + (size_t)b*NN*NN);
    const char* Xhb = (const char*)(Xh + (size_t)b*MPAD*NN);
    const char* Xlb = (const char*)(Xl + (size_t)b*MPAD*NN);

    const char* asrc[4];
    int adst[4];
    const char* xsrc[4];
    int xdst[4];
    {
        const char* Abase = Ab + (size_t)n0*2048;
        const char* Xb0 = Xhb + (size_t)(my*64)*2048;
        const char* Xb1 = Xlb + (size_t)(my*64)*2048;
        #pragma unroll
        for (int rr = 0; rr < 4; ++rr) {
            int q = rr*4 + w;
            int slot = q*64 + lane;
            int row = slot >> 3, ch = slot & 7;
            asrc[rr] = Abase + (size_t)row*2048 + ((ch ^ (row & 7)) << 4);
            adst[rr] = q*1024;
            int xrow = row & 63;
            xsrc[rr] = ((q >> 3) ? Xb1 : Xb0) + (size_t)xrow*2048 + ((ch ^ (xrow & 7)) << 4);
            xdst[rr] = q*1024;
        }
    }

    const int wm = (w >> 1) * 32, wn = (w & 1) * 64;
    const int kh = lane >> 5;
    const int arow = wm + (lane & 31);
    const int brow0 = wn + (lane & 31);
    const int brow1 = brow0 + 32;
    const int swa = arow & 7, swb0 = brow0 & 7, swb1 = brow1 & 7;

    f32x16 acc0 = {}, acc1 = {};

    auto stage = [&](int buf, int it) {
        size_t koff = (size_t)it * 128;
        #pragma unroll
        for (int rr = 0; rr < 4; ++rr)
            gload16(asrc[rr] + koff, (char*)As[buf] + adst[rr]);
        #pragma unroll
        for (int rr = 0; rr < 4; ++rr)
            gload16(xsrc[rr] + koff, (char*)Xs[buf] + xdst[rr]);
    };
    auto compute = [&](int buf) {
        const char* aP0 = (const char*)Xs[buf] + (size_t)arow*128;
        const char* aP1 = aP0 + 8192;
        const char* bP0 = (const char*)As[buf] + (size_t)brow0*128;
        const char* bP1 = (const char*)As[buf] + (size_t)brow1*128;
        #pragma unroll
        for (int s = 0; s < 4; ++s) {
            int cn = s*2 + kh;
            f16x8 ah = *(const f16x8*)(aP0 + ((cn ^ swa) << 4));
            f16x8 al = *(const f16x8*)(aP1 + ((cn ^ swa) << 4));
            f16x8 b0 = *(const f16x8*)(bP0 + ((cn ^ swb0) << 4));
            f16x8 b1 = *(const f16x8*)(bP1 + ((cn ^ swb1) << 4));
            acc0 = __builtin_amdgcn_mfma_f32_32x32x16_f16(ah, b0, acc0, 0, 0, 0);
            acc1 = __builtin_amdgcn_mfma_f32_32x32x16_f16(ah, b1, acc1, 0, 0, 0);
            acc0 = __builtin_amdgcn_mfma_f32_32x32x16_f16(al, b0, acc0, 0, 0, 0);
            acc1 = __builtin_amdgcn_mfma_f32_32x32x16_f16(al, b1, acc1, 0, 0, 0);
        }
    };

    stage(0, 0);
    int cur = 0;
    for (int it = 0; it < 15; ++it) {
        stage(cur ^ 1, it + 1);
        asm volatile("s_waitcnt vmcnt(8)" ::: "memory");
        __builtin_amdgcn_s_barrier();
        compute(cur);
        __builtin_amdgcn_s_barrier();
        cur ^= 1;
    }
    asm volatile("s_waitcnt vmcnt(0)" ::: "memory");
    __builtin_amdgcn_s_barrier();
    compute(cur);

    const int coll = lane & 31;
    #pragma unroll
    for (int reg = 0; reg < 16; ++reg) {
        int m = my*64 + wm + (reg & 3) + 8*(reg >> 2) + 4*kh;
        if (m < MROWS) {
            size_t o0 = ((size_t)b*MPAD + m)*NN + n0 + wn + coll;
            float v0 = acc0[reg], v1 = acc1[reg];
            if (HOP1) {
                f16 h0 = (f16)v0; Ch[o0]      = h0; Cl[o0]      = (f16)(v0 - (float)h0);
                f16 h1 = (f16)v1; Ch[o0 + 32] = h1; Cl[o0 + 32] = (f16)(v1 - (float)h1);
            } else {
                Cf[o0] = v0; Cf[o0 + 32] = v1;
            }
        }
    }
}

// ---------------- fused epilogue(layer) + fc(layer+1), weights via uniform s_load ----------------
__global__ __launch_bounds__(256) void k_epifc(float* __restrict__ x,
                      f16* __restrict__ xh, f16* __restrict__ xl,
                      const f16* __restrict__ h1h, const f16* __restrict__ h1l,
                      const float* __restrict__ h2,
                      const float* __restrict__ inp, const float* __restrict__ gw,
                      const float* __restrict__ gb, const float* __restrict__ bnb,
                      const float* __restrict__ tab,
                      const float* __restrict__ fc1, const float* __restrict__ fc2,
                      const float* __restrict__ skw, const float* __restrict__ skb,
                      float* __restrict__ skip, int layer) {
    int t = threadIdx.x;
    const int nl = layer + 1;
    const float* Wg  = gw  + layer*768;     // uniform bases -> scalar loads
    const float* GB  = gb  + layer*16;
    const float* BNB = bnb + layer*16;
    const float* BNS = tab + layer*16;
    const float* AC  = tab + 128 + layer*16;
    const float* BC  = tab + 256 + layer*16;
    const float* W3  = skw + nl*128;
    const float* B3  = skb + nl*8;

    int idx = blockIdx.x*256 + t;
    int n = idx & 1023;
    int q = idx >> 10;
    int l = q % 13, b = q / 13;
    float u1 = (l == 0) ? 0.f : inp[((size_t)(b*2 + 1)*NN + n)*NT + (l - 1)];
    float vx[16], v1[16], v2[16], xnew[16];
    #pragma unroll
    for (int c = 0; c < 16; c++) {
        size_t op = ((size_t)b*MPAD + c*13 + l)*NN + n;
        vx[c] = (float)xh[op] + (float)xl[op];
        v1[c] = (float)h1h[op] + (float)h1l[op];
        v2[c] = h2[op];
    }
    #pragma unroll
    for (int o = 0; o < 16; o++) {
        float s = GB[o];
        #pragma unroll
        for (int c = 0; c < 16; c++) s += Wg[o*48 + c]      * vx[c];
        #pragma unroll
        for (int c = 0; c < 16; c++) s += Wg[o*48 + 16 + c] * v1[c];
        #pragma unroll
        for (int c = 0; c < 16; c++) s += Wg[o*48 + 32 + c] * v2[c];
        float xa = AC[o]*u1 + BC[o];
        float vo = x[((size_t)b*MROWS + o*13 + l)*NN + n];
        xnew[o] = BNS[o]*(s + xa + vo) + BNB[o];
    }
    if (layer < 6) {
        #pragma unroll
        for (int o = 0; o < 16; o++)
            x[((size_t)b*MROWS + o*13 + l)*NN + n] = xnew[o];
    }
    float t1[16], vs[16];
    #pragma unroll
    for (int c = 0; c < 16; c++) {
        float s = 0.f;
        #pragma unroll
        for (int j = 0; j < 16; j++) s += fc1[c*16 + j] * xnew[j];
        t1[c] = fmaxf(s, 0.f);
    }
    #pragma unroll
    for (int c = 0; c < 16; c++) {
        float s = 0.f;
        #pragma unroll
        for (int j = 0; j < 16; j++) s += fc2[c*16 + j] * t1[j];
        float z = 2.f*s + xnew[c];
        vs[c] = 1.f / (1.f + __expf(-z));
        if (layer < 6) {
            size_t o = ((size_t)b*MPAD + c*13 + l)*NN + n;
            f16 hi = (f16)vs[c];
            xh[o] = hi;
            xl[o] = (f16)(vs[c] - (float)hi);
        }
    }
    #pragma unroll
    for (int sc = 0; sc < 8; sc++) {
        float s = B3[sc];
        #pragma unroll
        for (int c = 0; c < 16; c++) s += W3[sc*16 + c] * vs[c];
        skip[((size_t)b*832 + (7 - nl)*104 + sc*13 + l)*NN + n] = s;
    }
}

// ---------------- end stage 1: split-K partial GEMM ----------------
__global__ __launch_bounds__(256) void k_end1(const float* __restrict__ skip, const float* __restrict__ w1,
                       float* __restrict__ out1) {
    __shared__ alignas(16) float Ws[52][68];
    __shared__ alignas(16) float Ss[52][68];
    int n0 = blockIdx.x * 64, ks = blockIdx.y, b = blockIdx.z;
    int t = threadIdx.x, ty = t >> 4, tx = t & 15;
    float acc[4][4] = {};
    int kbase = ks * 208;
    for (int kk = 0; kk < 4; kk++) {
        int k0 = kbase + kk*52;
        for (int i = t; i < 52*64; i += 256) {
            int r = i >> 6, c = i & 63;
            float sv = skip[((size_t)b*832 + k0 + r)*NN + n0 + c];
            Ss[r][c] = sv > 0.f ? sv : 0.f;
            Ws[r][c] = w1[(size_t)c*832 + k0 + r];
        }
        __syncthreads();
        #pragma unroll 4
        for (int k = 0; k < 52; k++) {
            float4 av = *(const float4*)&Ws[k][ty*4];
            float4 bv = *(const float4*)&Ss[k][tx*4];
            float a[4] = {av.x, av.y, av.z, av.w};
            float bb[4] = {bv.x, bv.y, bv.z, bv.w};
            #pragma unroll
            for (int i = 0; i < 4; i++)
                #pragma unroll
                for (int jj = 0; jj < 4; jj++) acc[i][jj] += a[i]*bb[jj];
        }
        __syncthreads();
    }
    #pragma unroll
    for (int i = 0; i < 4; i++)
        #pragma unroll
        for (int jj = 0; jj < 4; jj++)
            out1[(((size_t)ks*NB + b)*64 + ty*4 + i)*NN + n0 + tx*4 + jj] = acc[i][jj];
}

// ---------------- end stage 2: combine partials, relu, 12x64 conv ----------------
__global__ __launch_bounds__(256) void k_end2(const float* __restrict__ out1, const float* __restrict__ b1,
                       const float* __restrict__ w2, const float* __restrict__ b2,
                       float* __restrict__ outp) {
    __shared__ float S[64][68];
    int n0 = blockIdx.x * 64, b = blockIdx.y;
    int t = threadIdx.x;
    for (int i = t; i < 4096; i += 256) {
        int o = i >> 6, n = i & 63;
        float s = b1[o];
        #pragma unroll
        for (int ks = 0; ks < 4; ks++)
            s += out1[(((size_t)ks*NB + b)*64 + o)*NN + n0 + n];
        S[o][n] = s > 0.f ? s : 0.f;
    }
    __syncthreads();
    for (int idx = t; idx < 12*64; idx += 256) {
        int jr = idx >> 6, n = idx & 63;
        float s = b2[jr];
        for (int o = 0; o < 64; o++) s += w2[jr*64 + o] * S[o][n];
        outp[((size_t)b*12 + jr)*NN + n0 + n] = s;
    }
}

extern "C" void kernel_launch(void* const* d_in, const int* in_sizes, int n_in,
                              void* d_out, int out_size, void* d_ws, size_t ws_size,
                              hipStream_t stream) {
    (void)in_sizes; (void)n_in; (void)out_size;
    if (ws_size < WS_FLOATS * sizeof(float)) return;

    const float* inputs  = (const float*)d_in[0];
    const int*   ind     = (const int*)  d_in[1];
    const float* start_w = (const float*)d_in[2];
    const float* start_b = (const float*)d_in[3];
    const float* starta_w= (const float*)d_in[4];
    const float* starta_b= (const float*)d_in[5];
    const float* p1      = (const float*)d_in[6];
    const float* p2      = (const float*)d_in[7];
    const float* p3      = (const float*)d_in[8];
    const float* pk      = (const float*)d_in[9];
    const float* fc1_w   = (const float*)d_in[10];
    const float* fc2_w   = (const float*)d_in[11];
    const float* skip_w  = (const float*)d_in[12];
    const float* skip_b  = (const float*)d_in[13];
    const float* gconv_w = (const float*)d_in[14];
    const float* gconv_b = (const float*)d_in[15];
    const float* bn_g    = (const float*)d_in[16];
    const float* bn_b    = (const float*)d_in[17];
    const float* bna_g   = (const float*)d_in[18];
    const float* bna_b   = (const float*)d_in[19];
    const float* end1_w  = (const float*)d_in[20];
    const float* end1_b  = (const float*)d_in[21];
    const float* end2_w  = (const float*)d_in[22];
    const float* end2_b  = (const float*)d_in[23];

    float* ws   = (float*)d_ws;
    float* tab  = ws + OFF_TAB;
    float* adpg = ws + OFF_ADP;
    float* Mg   = ws + OFF_M;
    float* src  = ws + OFF_SRC;
    float* temp = ws + OFF_TEMP;
    f16*   Ah   = (f16*)(ws + OFF_AH);
    f16*   xh   = (f16*)(ws + OFF_XH);
    f16*   xl   = (f16*)(ws + OFF_XL);
    f16*   h1h  = (f16*)(ws + OFF_H1H);
    f16*   h1l  = (f16*)(ws + OFF_H1L);
    float* h2   = ws + OFF_H2;               // reused as out1 partials after layer loop
    float* x    = ws + OFF_X;
    float* skip = ws + OFF_SKIP;

    k_tables<<<1, 64, 0, stream>>>(bn_g, bna_g, bna_b, starta_w, starta_b, tab);
    k_startfc<<<(NB*NL*NN)/256, 256, 0, stream>>>(inputs, start_w, start_b, fc1_w, fc2_w,
                                                  skip_w, skip_b, x, xh, xl, skip);
    k_adp<<<NB, 256, 0, stream>>>(p1, ind, pk, p3, adpg, Mg);
    k_st<<<dim3(8, NB), 256, 0, stream>>>(p2, adpg, Mg, src, temp);
    k_A<<<dim3(136, 1, NB), 256, 0, stream>>>(src, temp, Ah);

    for (int i = 0; i < 7; i++) {            // layer 7's gemms/epilogue are dead code
        k_gmm<true ><<<512, 256, 0, stream>>>(xh,  xl,  Ah, nullptr, h1h, h1l);
        k_gmm<false><<<512, 256, 0, stream>>>(h1h, h1l, Ah, h2, nullptr, nullptr);
        k_epifc<<<(NB*NL*NN)/256, 256, 0, stream>>>(x, xh, xl, h1h, h1l, h2, inputs,
                                                    gconv_w, gconv_b, bn_b, tab,
                                                    fc1_w, fc2_w, skip_w, skip_b, skip, i);
    }
    k_end1<<<dim3(16, 4, NB), 256, 0, stream>>>(skip, end1_w, h2);
    k_end2<<<dim3(16, NB), 256, 0, stream>>>(h2, end1_b, end2_w, end2_b, (float*)d_out);
}